// Round 21
// baseline (91.796 us; speedup 1.0000x reference)
//
#include <hip/hip_runtime.h>
#include <stdint.h>

// N = D*H*W = 8*32*32 voxels; C = 64 channels.
constexpr int N = 8192;
// softmax scale (1/sqrt(64)) * log2(e), folded into Q (attn works in exp2 domain).
constexpr float QSCALE = 0.18033688011112042f;
constexpr int SPLIT = 4;   // KV chunks per dir; slice = dir*4+chunk pinned per-XCD

typedef __attribute__((ext_vector_type(4))) float f32x4;
typedef __attribute__((ext_vector_type(16))) float f32x16;
typedef __attribute__((ext_vector_type(4))) unsigned int u32x4;
typedef __attribute__((ext_vector_type(2))) unsigned int u32x2;
typedef __attribute__((ext_vector_type(4))) unsigned short u16x4;
typedef __attribute__((ext_vector_type(8))) __bf16 bf16x8;

__device__ inline unsigned short f2bf(float f) {
  unsigned u = __builtin_bit_cast(unsigned, f);
  u += 0x7FFFu + ((u >> 16) & 1u);
  return (unsigned short)(u >> 16);
}
__device__ inline float bf2f(unsigned short u) {
  return __builtin_bit_cast(float, (unsigned)u << 16);
}
// pack two f32 -> two bf16 in one u32 (low=a, high=b)
__device__ inline unsigned cvtpk(float a, float b) {
  unsigned r;
  asm("v_cvt_pk_bf16_f32 %0, %1, %2" : "=v"(r) : "v"(a), "v"(b));
  return r;
}

// 32x32x16 bf16 MFMA via builtin (compiler-visible scheduling, R18-proven).
// A: lane holds A[lane&31][8*(lane>>5)+e]; B: B[8*(lane>>5)+e][lane&31];
// D: col=lane&31, row=(r&3)+8*(r>>2)+4*(lane>>5), r=0..15 (m74/m101-verified).
__device__ inline void mfma32(f32x16& d, u32x4 a, u32x4 b) {
  d = __builtin_amdgcn_mfma_f32_32x32x16_bf16(
      __builtin_bit_cast(bf16x8, a), __builtin_bit_cast(bf16x8, b), d, 0, 0, 0);
}

struct ProjArgs {
  const float* x[6];
  const float* w[6];
  const float* b[6];
  unsigned short* o[6];
  int mode[6];     // 0: out[n][64]   1: out[c][N]
  float scale[6];
};

// ---- 1x1x1 conv projections (R20-verbatim). 64-voxel tiles, grid (128,6).
__global__ __launch_bounds__(256) void proj_kernel(ProjArgs A) {
  const int p = blockIdx.y;
  const float* __restrict__ x = A.x[p];
  const float* __restrict__ w = A.w[p];
  const float* __restrict__ bias = A.b[p];
  unsigned short* __restrict__ out = A.o[p];
  const int n0 = blockIdx.x * 64;
  __shared__ float Xs[64][64];    // 16 KB
  __shared__ float Ws[64][64];    // 16 KB
  const int t = threadIdx.x;
#pragma unroll
  for (int i = 0; i < 4; i++) {
    int s = t + i * 256;
    ((u32x4*)Ws)[s] = ((const u32x4*)w)[s];
  }
#pragma unroll
  for (int i = 0; i < 4; i++) {
    int s = t + i * 256;
    int c = s >> 4, nc = s & 15;
    *(u32x4*)&Xs[c][nc * 4] = *(const u32x4*)&x[c * N + n0 + nc * 4];
  }
  __syncthreads();
  const int n = t & 63, h = t >> 6;
  float acc[16];
#pragma unroll
  for (int o = 0; o < 16; o++) acc[o] = bias[h * 16 + o];
  for (int c = 0; c < 64; c++) {
    float xv = Xs[c][n];
#pragma unroll
    for (int o = 0; o < 16; o++) acc[o] = fmaf(Ws[h * 16 + o][c], xv, acc[o]);
  }
  const float sc = A.scale[p];
  if (A.mode[p] == 0) {
    unsigned short* po = out + (size_t)(n0 + n) * 64 + h * 16;
#pragma unroll
    for (int o = 0; o < 16; o++) po[o] = f2bf(acc[o] * sc);
  } else {
#pragma unroll
    for (int o = 0; o < 16; o++) out[(size_t)(h * 16 + o) * N + n0 + n] = f2bf(acc[o] * sc);
  }
}

// ---- flash cross-attention: ZERO-LDS main loop. K/V fragments read directly from
// global (L2-hot via XCD slicing); kf double-buffered across iterations (named
// kfA/kfB -> compiler cannot sink the load to its use); vf issued at iter top,
// consumed ~200 issue-cycles later at PV. No barriers, no DMA, no LDS in loop.
// Grid 512: slice=bid&7 (per-XCD), qb=bid>>3 (0..63, 128 Q rows/block).
// 4 waves = 2 qsub (q=64 each) x 2 jsub (j=32 halves of each 64-j tile).
// 32x32 swapped-QK, in-register P (cvt_pk + permlane32_swap). LDS only for merge.
__global__ __launch_bounds__(256, 2) void attn_kernel(
    const unsigned short* __restrict__ Q0, const unsigned short* __restrict__ K0,
    const unsigned short* __restrict__ V0, const unsigned short* __restrict__ Q1,
    const unsigned short* __restrict__ K1, const unsigned short* __restrict__ V1,
    unsigned short* __restrict__ Opart, float* __restrict__ Lsum) {
  const int bid = blockIdx.x;
  const int slice = bid & 7;        // -> XCD (round-robin dispatch)
  const int qb = bid >> 3;          // 0..63, 128 Q rows each
  const int dir = slice >> 2;
  const int chunk = slice & 3;
  const unsigned short* __restrict__ Q = dir ? Q1 : Q0;
  const unsigned short* __restrict__ K = dir ? K1 : K0;
  const unsigned short* __restrict__ V = dir ? V1 : V0;

  __shared__ char smem[33280];  // merge only: [0,32K) obuf x2 qsub; [32K,+512) mlb

  const int t = threadIdx.x;
  const int lane = t & 63, w = t >> 6;
  const int qsub = w >> 1, jsub = w & 1;
  const int hi = lane >> 5, l31 = lane & 31;
  const int kvbase = chunk * 2048;
  const char* const Kc = (const char*)K;
  const char* const Vc = (const char*)V;

  // K A-frag loads: kf[ks] = K[row][ks*16+8hi ..+8] = 16B at row*128 + (2ks+hi)*16
#define LOADK(jt, kf)                                                          \
  do {                                                                         \
    const size_t row_ = (size_t)(kvbase + (jt) * 64 + jsub * 32 + l31);        \
    _Pragma("unroll") for (int ks = 0; ks < 4; ks++)                           \
      kf[ks] = *(const u32x4*)(Kc + row_ * 128 + (2 * ks + hi) * 16);          \
  } while (0)
  // V A-frag loads: vf[cb][js] = V[cb*32+l31][jb + (js*2+hi)*8 ..+8]
#define LOADV(jt, vf)                                                          \
  do {                                                                         \
    const int jb_ = kvbase + (jt) * 64 + jsub * 32;                            \
    _Pragma("unroll") for (int cb = 0; cb < 2; cb++) {                         \
      const size_t vr_ = (size_t)(cb * 32 + l31) * (N * 2);                    \
      _Pragma("unroll") for (int js = 0; js < 2; js++)                         \
        vf[cb][js] = *(const u32x4*)(Vc + vr_ +                                \
                                     (size_t)(jb_ + (js * 2 + hi) * 8) * 2);   \
    }                                                                          \
  } while (0)

  // Q^T B-fragments (held whole kernel): qf[qs][ks] = Q[qrow][ks*16+8hi .. +8]
  u32x4 qf[2][4];
#pragma unroll
  for (int qs = 0; qs < 2; qs++) {
    const int qrow = qb * 128 + qsub * 64 + qs * 32 + l31;
#pragma unroll
    for (int ks = 0; ks < 4; ks++)
      qf[qs][ks] = *(const u32x4*)((const char*)Q + (size_t)qrow * 128 + (2 * ks + hi) * 16);
  }

  f32x16 acc[2][2];   // O^T[ch=cb*32+crow(r,hi)][q=qsub*64+qs*32+l31], partial (jsub)
#pragma unroll
  for (int cb = 0; cb < 2; cb++)
#pragma unroll
    for (int qs = 0; qs < 2; qs++)
#pragma unroll
      for (int r = 0; r < 16; r++) acc[cb][qs][r] = 0.f;
  float lpart[2] = {0.f, 0.f};

// one iteration: consume kfC (tile jt), prefetch kfN (tile jt+1), load+use vf.
#define BODY(jt, kfC, kfN)                                                     \
  do {                                                                         \
    u32x4 vf[2][2];                                                            \
    LOADV(jt, vf);                          /* in flight until PV */           \
    if ((jt) + 1 < 32) LOADK((jt) + 1, kfN); /* consumed NEXT iter */          \
    f32x16 st[2];                                                              \
    _Pragma("unroll") for (int qs = 0; qs < 2; qs++)                           \
      _Pragma("unroll") for (int r = 0; r < 16; r++) st[qs][r] = 0.f;          \
    __builtin_amdgcn_s_setprio(1);                                             \
    _Pragma("unroll") for (int ks = 0; ks < 4; ks++) {                         \
      mfma32(st[0], kfC[ks], qf[0][ks]);                                       \
      mfma32(st[1], kfC[ks], qf[1][ks]);                                       \
    }                                                                          \
    __builtin_amdgcn_s_setprio(0);                                             \
    _Pragma("unroll") for (int qs = 0; qs < 2; qs++) {                         \
      float p[16];                                                             \
      _Pragma("unroll") for (int r = 0; r < 16; r++)                           \
        p[r] = __builtin_amdgcn_exp2f(st[qs][r]);                              \
      lpart[qs] += (((p[0]+p[1])+(p[2]+p[3]))+((p[4]+p[5])+(p[6]+p[7]))) +     \
                   (((p[8]+p[9])+(p[10]+p[11]))+((p[12]+p[13])+(p[14]+p[15])));\
      unsigned w00 = cvtpk(p[0], p[1]),   w01 = cvtpk(p[2], p[3]);             \
      unsigned w10 = cvtpk(p[4], p[5]),   w11 = cvtpk(p[6], p[7]);             \
      unsigned w20 = cvtpk(p[8], p[9]),   w21 = cvtpk(p[10], p[11]);           \
      unsigned w30 = cvtpk(p[12], p[13]), w31 = cvtpk(p[14], p[15]);           \
      asm volatile("v_permlane32_swap_b32 %0, %1" : "+v"(w00), "+v"(w10));     \
      asm volatile("v_permlane32_swap_b32 %0, %1" : "+v"(w01), "+v"(w11));     \
      asm volatile("v_permlane32_swap_b32 %0, %1" : "+v"(w20), "+v"(w30));     \
      asm volatile("v_permlane32_swap_b32 %0, %1" : "+v"(w21), "+v"(w31));     \
      u32x4 pf0, pf1;                                                          \
      pf0[0] = w00; pf0[1] = w01; pf0[2] = w10; pf0[3] = w11;                  \
      pf1[0] = w20; pf1[1] = w21; pf1[2] = w30; pf1[3] = w31;                  \
      __builtin_amdgcn_s_setprio(1);                                           \
      mfma32(acc[0][qs], vf[0][0], pf0);                                       \
      mfma32(acc[1][qs], vf[1][0], pf0);                                       \
      mfma32(acc[0][qs], vf[0][1], pf1);                                       \
      mfma32(acc[1][qs], vf[1][1], pf1);                                       \
      __builtin_amdgcn_s_setprio(0);                                           \
    }                                                                          \
  } while (0)

  u32x4 kfA[4], kfB[4];
  LOADK(0, kfA);
  for (int jt = 0; jt < 32; jt += 2) {
    BODY(jt, kfA, kfB);
    BODY(jt + 1, kfB, kfA);
  }
#undef BODY
#undef LOADK
#undef LOADV

  // full l per q over this wave's j32: add partner hi-half
#pragma unroll
  for (int qs = 0; qs < 2; qs++) lpart[qs] += __shfl_xor(lpart[qs], 32);

  // ---- jsub merge (plain sums; LDS obuf)
  __syncthreads();
  char* const obuf = smem + qsub * 16384;    // [64 q][64 ch] f32, XOR-swizzled
  float* const mlb = (float*)(smem + 32768); // [2 qsub][64 q] partner l
  if (jsub == 1) {
#pragma unroll
    for (int qs = 0; qs < 2; qs++) {
      const int qloc = qs * 32 + l31;
      const int qsw = (qloc & 7) << 4;
#pragma unroll
      for (int cb = 0; cb < 2; cb++)
#pragma unroll
        for (int a = 0; a < 4; a++) {
          const int ch0 = cb * 32 + 8 * a + 4 * hi;
          f32x4 v;
          v[0] = acc[cb][qs][4 * a];     v[1] = acc[cb][qs][4 * a + 1];
          v[2] = acc[cb][qs][4 * a + 2]; v[3] = acc[cb][qs][4 * a + 3];
          *(f32x4*)(obuf + qloc * 256 + ((ch0 * 4) ^ qsw)) = v;
        }
      if (hi == 0) mlb[qsub * 64 + qloc] = lpart[qs];
    }
  }
  __syncthreads();
  if (jsub == 0) {
#pragma unroll
    for (int qs = 0; qs < 2; qs++) {
      const int qloc = qs * 32 + l31;
      const int qsw = (qloc & 7) << 4;
      const int qg = qb * 128 + qsub * 64 + qloc;
      const size_t pbase = ((size_t)slice * N + qg) * 64;
#pragma unroll
      for (int cb = 0; cb < 2; cb++)
#pragma unroll
        for (int a = 0; a < 4; a++) {
          const int ch0 = cb * 32 + 8 * a + 4 * hi;
          f32x4 oo = *(const f32x4*)(obuf + qloc * 256 + ((ch0 * 4) ^ qsw));
          u32x2 pk;
          pk[0] = cvtpk(acc[cb][qs][4 * a] + oo[0], acc[cb][qs][4 * a + 1] + oo[1]);
          pk[1] = cvtpk(acc[cb][qs][4 * a + 2] + oo[2], acc[cb][qs][4 * a + 3] + oo[3]);
          *(u32x2*)(Opart + pbase + ch0) = pk;
        }
      if (hi == 0) Lsum[(size_t)slice * N + qg] = lpart[qs] + mlb[qsub * 64 + qloc];
    }
  }
}

// ---- fused merge + output projection (R20-verbatim): 32-voxel tiles, grid 256.
__global__ __launch_bounds__(256) void oproj_kernel(
    const unsigned short* __restrict__ Opart, const float* __restrict__ Lsum,
    const float* __restrict__ wo, const float* __restrict__ bo,
    float* __restrict__ out) {
  __shared__ float Fs[128][32];   // 16 KB
  __shared__ float Ws[64][128];   // 32 KB
  const int t = threadIdx.x;
  const int n0 = blockIdx.x * 32;
#pragma unroll
  for (int i = 0; i < 8; i++) {
    int s = t + i * 256;
    ((u32x4*)Ws)[s] = ((const u32x4*)wo)[s];
  }
  const int q = t & 31;     // local voxel
  const int cg = t >> 5;    // 8 groups: 2 ch4-blocks each per dir
#pragma unroll
  for (int dir = 0; dir < 2; dir++) {
    float lt = 0.f;
#pragma unroll
    for (int c = 0; c < 4; c++) lt += Lsum[(size_t)(dir * SPLIT + c) * N + n0 + q];
    const float rD = 1.0f / lt;
#pragma unroll
    for (int i = 0; i < 2; i++) {
      const int ch4 = cg * 2 + i;   // channels ch4*4 .. +4
      float s0 = 0.f, s1 = 0.f, s2 = 0.f, s3 = 0.f;
#pragma unroll
      for (int c = 0; c < 4; c++) {
        u16x4 v = *(const u16x4*)(Opart +
            ((size_t)(dir * SPLIT + c) * N + n0 + q) * 64 + ch4 * 4);
        s0 += bf2f(v[0]); s1 += bf2f(v[1]); s2 += bf2f(v[2]); s3 += bf2f(v[3]);
      }
      Fs[dir * 64 + ch4 * 4 + 0][q] = s0 * rD;
      Fs[dir * 64 + ch4 * 4 + 1][q] = s1 * rD;
      Fs[dir * 64 + ch4 * 4 + 2][q] = s2 * rD;
      Fs[dir * 64 + ch4 * 4 + 3][q] = s3 * rD;
    }
  }
  __syncthreads();
  const int n = t & 31, h = t >> 5;   // 8 outputs per thread
  float acc[8];
#pragma unroll
  for (int o = 0; o < 8; o++) acc[o] = bo[h * 8 + o];
  for (int ch = 0; ch < 128; ch++) {
    float fv = Fs[ch][n];
#pragma unroll
    for (int o = 0; o < 8; o++) acc[o] = fmaf(Ws[h * 8 + o][ch], fv, acc[o]);
  }
#pragma unroll
  for (int o = 0; o < 8; o++) out[(size_t)(h * 8 + o) * N + n0 + n] = acc[o];
}

extern "C" void kernel_launch(void* const* d_in, const int* in_sizes, int n_in,
                              void* d_out, int out_size, void* d_ws, size_t ws_size,
                              hipStream_t stream) {
  const float* ct     = (const float*)d_in[0];
  const float* mri    = (const float*)d_in[1];
  const float* wq_ct  = (const float*)d_in[2];
  const float* bq_ct  = (const float*)d_in[3];
  const float* wk_mri = (const float*)d_in[4];
  const float* bk_mri = (const float*)d_in[5];
  const float* wv_mri = (const float*)d_in[6];
  const float* bv_mri = (const float*)d_in[7];
  const float* wq_mri = (const float*)d_in[8];
  const float* bq_mri = (const float*)d_in[9];
  const float* wk_ct  = (const float*)d_in[10];
  const float* bk_ct  = (const float*)d_in[11];
  const float* wv_ct  = (const float*)d_in[12];
  const float* bv_ct  = (const float*)d_in[13];
  const float* wo     = (const float*)d_in[14];
  const float* bo     = (const float*)d_in[15];

  // ws layout: [0,6M) 6x1MB bf16 projections; [6M,14M) Opart bf16; [14M,14.5M) Lsum f32.
  char* ws = (char*)d_ws;
  const size_t MB = (size_t)1 << 20;
  unsigned short* Qt_ct  = (unsigned short*)(ws + 0 * MB);  // [n][64], pre-scaled
  unsigned short* Kt_mri = (unsigned short*)(ws + 1 * MB);  // [n][64]
  unsigned short* V_mri  = (unsigned short*)(ws + 2 * MB);  // [c][N]
  unsigned short* Qt_mri = (unsigned short*)(ws + 3 * MB);
  unsigned short* Kt_ct  = (unsigned short*)(ws + 4 * MB);
  unsigned short* V_ct   = (unsigned short*)(ws + 5 * MB);
  unsigned short* Opart  = (unsigned short*)(ws + 6 * MB);
  float* Lsum            = (float*)(ws + 14 * MB);

  ProjArgs A;
  A.x[0] = ct;  A.w[0] = wq_ct;  A.b[0] = bq_ct;  A.o[0] = Qt_ct;  A.mode[0] = 0; A.scale[0] = QSCALE;
  A.x[1] = mri; A.w[1] = wk_mri; A.b[1] = bk_mri; A.o[1] = Kt_mri; A.mode[1] = 0; A.scale[1] = 1.f;
  A.x[2] = mri; A.w[2] = wv_mri; A.b[2] = bv_mri; A.o[2] = V_mri;  A.mode[2] = 1; A.scale[2] = 1.f;
  A.x[3] = mri; A.w[3] = wq_mri; A.b[3] = bq_mri; A.o[3] = Qt_mri; A.mode[3] = 0; A.scale[3] = QSCALE;
  A.x[4] = ct;  A.w[4] = wk_ct;  A.b[4] = bk_ct;  A.o[4] = Kt_ct;  A.mode[4] = 0; A.scale[4] = 1.f;
  A.x[5] = ct;  A.w[5] = wv_ct;  A.b[5] = bv_ct;  A.o[5] = V_ct;   A.mode[5] = 1; A.scale[5] = 1.f;

  proj_kernel<<<dim3(128, 6), 256, 0, stream>>>(A);
  attn_kernel<<<dim3(512), 256, 0, stream>>>(Qt_ct, Kt_mri, V_mri,
                                             Qt_mri, Kt_ct, V_ct, Opart, Lsum);
  oproj_kernel<<<dim3(256), 256, 0, stream>>>(Opart, Lsum, wo, bo, (float*)d_out);
}

// Round 22
// 68.604 us; speedup vs baseline: 1.3381x; 1.3381x over previous
//
#include <hip/hip_runtime.h>
#include <stdint.h>

// N = D*H*W = 8*32*32 voxels; C = 64 channels.
constexpr int N = 8192;
// softmax scale (1/sqrt(64)) * log2(e), folded into Q (attn works in exp2 domain).
constexpr float QSCALE = 0.18033688011112042f;
constexpr int SPLIT = 4;   // KV chunks per dir; slice = dir*4+chunk pinned per-XCD

typedef __attribute__((ext_vector_type(4))) float f32x4;
typedef __attribute__((ext_vector_type(16))) float f32x16;
typedef __attribute__((ext_vector_type(4))) unsigned int u32x4;
typedef __attribute__((ext_vector_type(2))) unsigned int u32x2;
typedef __attribute__((ext_vector_type(4))) unsigned short u16x4;
typedef __attribute__((ext_vector_type(8))) __bf16 bf16x8;

__device__ inline unsigned short f2bf(float f) {
  unsigned u = __builtin_bit_cast(unsigned, f);
  u += 0x7FFFu + ((u >> 16) & 1u);
  return (unsigned short)(u >> 16);
}
__device__ inline float bf2f(unsigned short u) {
  return __builtin_bit_cast(float, (unsigned)u << 16);
}
// pack two f32 -> two bf16 in one u32 (low=a, high=b)
__device__ inline unsigned cvtpk(float a, float b) {
  unsigned r;
  asm("v_cvt_pk_bf16_f32 %0, %1, %2" : "=v"(r) : "v"(a), "v"(b));
  return r;
}

// 32x32x16 bf16 MFMA via builtin (compiler-visible scheduling, R18-proven).
// A: lane holds A[lane&31][8*(lane>>5)+e]; B: B[8*(lane>>5)+e][lane&31];
// D: col=lane&31, row=(r&3)+8*(r>>2)+4*(lane>>5), r=0..15 (m74/m101-verified).
__device__ inline void mfma32(f32x16& d, u32x4 a, u32x4 b) {
  d = __builtin_amdgcn_mfma_f32_32x32x16_bf16(
      __builtin_bit_cast(bf16x8, a), __builtin_bit_cast(bf16x8, b), d, 0, 0, 0);
}
// async 16B global -> LDS DMA (LDS dst wave-uniform; global src per-lane)
__device__ inline void gload16(const void* src, void* lds) {
  __builtin_amdgcn_global_load_lds(
      (const __attribute__((address_space(1))) unsigned int*)src,
      (__attribute__((address_space(3))) unsigned int*)lds, 16, 0, 0);
}

struct ProjArgs {
  const float* x[6];
  const float* w[6];
  const float* b[6];
  unsigned short* o[6];
  int mode[6];     // 0: out[n][64]   1: out[c][N]
  float scale[6];
};

// ---- 1x1x1 conv projections (R14-best tail config). 64-voxel tiles, grid (128,6).
__global__ __launch_bounds__(256) void proj_kernel(ProjArgs A) {
  const int p = blockIdx.y;
  const float* __restrict__ x = A.x[p];
  const float* __restrict__ w = A.w[p];
  const float* __restrict__ bias = A.b[p];
  unsigned short* __restrict__ out = A.o[p];
  const int n0 = blockIdx.x * 64;
  __shared__ float Xs[64][64];    // 16 KB
  __shared__ float Ws[64][64];    // 16 KB
  const int t = threadIdx.x;
#pragma unroll
  for (int i = 0; i < 4; i++) {          // W: 4096 f32 = 1024 16B slots
    int s = t + i * 256;
    ((u32x4*)Ws)[s] = ((const u32x4*)w)[s];
  }
#pragma unroll
  for (int i = 0; i < 4; i++) {          // X tile: 64x64 f32 = 1024 slots
    int s = t + i * 256;
    int c = s >> 4, nc = s & 15;
    *(u32x4*)&Xs[c][nc * 4] = *(const u32x4*)&x[c * N + n0 + nc * 4];
  }
  __syncthreads();
  const int n = t & 63, h = t >> 6;
  float acc[16];
#pragma unroll
  for (int o = 0; o < 16; o++) acc[o] = bias[h * 16 + o];
  for (int c = 0; c < 64; c++) {
    float xv = Xs[c][n];
#pragma unroll
    for (int o = 0; o < 16; o++) acc[o] = fmaf(Ws[h * 16 + o][c], xv, acc[o]);
  }
  const float sc = A.scale[p];
  if (A.mode[p] == 0) {
    unsigned short* po = out + (size_t)(n0 + n) * 64 + h * 16;
#pragma unroll
    for (int o = 0; o < 16; o++) po[o] = f2bf(acc[o] * sc);
  } else {
#pragma unroll
    for (int o = 0; o < 16; o++) out[(size_t)(h * 16 + o) * N + n0 + n] = f2bf(acc[o] * sc);
  }
}

// ---- flash cross-attention (R18 verbatim — best measured: 47.0 us).
// 32x32 swapped-QK, in-register P (cvt_pk + permlane32_swap), dbuf DMA staging,
// builtin MFMA (compiler-scheduled). Grid 512: slice=bid&7 (per-XCD), qb=bid>>3.
// 4 waves = 2 qsub (q=64 each) x 2 jsub (j=32 halves of the shared 64-j tile).
__global__ __launch_bounds__(256, 2) void attn_kernel(
    const unsigned short* __restrict__ Q0, const unsigned short* __restrict__ K0,
    const unsigned short* __restrict__ V0, const unsigned short* __restrict__ Q1,
    const unsigned short* __restrict__ K1, const unsigned short* __restrict__ V1,
    unsigned short* __restrict__ Opart, float* __restrict__ Lsum) {
  const int bid = blockIdx.x;
  const int slice = bid & 7;        // -> XCD (round-robin dispatch)
  const int qb = bid >> 3;          // 0..63, 128 Q rows each
  const int dir = slice >> 2;
  const int chunk = slice & 3;
  const unsigned short* __restrict__ Q = dir ? Q1 : Q0;
  const unsigned short* __restrict__ K = dir ? K1 : K0;
  const unsigned short* __restrict__ V = dir ? V1 : V0;

  __shared__ char smem[33280];  // [0,16K) K dbuf; [16K,32K) V dbuf; [32K,+512) mlb

  const int t = threadIdx.x;
  const int lane = t & 63, w = t >> 6;
  const int qsub = w >> 1, jsub = w & 1;
  const int hi = lane >> 5, l31 = lane & 31;
  const int kvbase = chunk * 2048;

  // staging geometry (R7..R18-proven): wave stages slots s=(w*2+i)*64+lane of
  // each 8KB tile; source col pre-swizzled so ds_read applies same XOR (rule #21).
  const int srowoff = lane >> 3;
  const int swzb = ((lane & 7) ^ (lane >> 3)) * 16;
  const char* const Kc = (const char*)K;
  const char* const Vc = (const char*)V;

#define STAGE(jtile, slot)                                                     \
  do {                                                                         \
    const int j0s = kvbase + (jtile) * 64;                                     \
    _Pragma("unroll") for (int i = 0; i < 2; i++) {                            \
      const int row = (w * 2 + i) * 8 + srowoff;                               \
      gload16(Kc + (size_t)(j0s + row) * 128 + swzb,                           \
              smem + (slot) * 8192 + (w * 2 + i) * 1024);                      \
      gload16(Vc + (size_t)row * (N * 2) + (size_t)j0s * 2 + swzb,             \
              smem + 16384 + (slot) * 8192 + (w * 2 + i) * 1024);              \
    }                                                                          \
  } while (0)

  // Q^T B-fragments (held whole kernel): qf[qs][ks] = Q[qrow][ks*16+8hi .. +8]
  u32x4 qf[2][4];
#pragma unroll
  for (int qs = 0; qs < 2; qs++) {
    const int qrow = qb * 128 + qsub * 64 + qs * 32 + l31;
#pragma unroll
    for (int ks = 0; ks < 4; ks++)
      qf[qs][ks] = *(const u32x4*)((const char*)Q + (size_t)qrow * 128 + (2 * ks + hi) * 16);
  }

  f32x16 acc[2][2];   // O^T[ch=cb*32+crow(r,hi)][q=qsub*64+qs*32+l31], partial (jsub)
#pragma unroll
  for (int cb = 0; cb < 2; cb++)
#pragma unroll
    for (int qs = 0; qs < 2; qs++)
#pragma unroll
      for (int r = 0; r < 16; r++) acc[cb][qs][r] = 0.f;
  float lpart[2] = {0.f, 0.f};

  STAGE(0, 0);
  for (int jt = 0; jt < 32; ++jt) {
    // own DMAs for tile jt landed; barrier joins all waves (their DMAs done too).
    asm volatile("s_waitcnt vmcnt(0)" ::: "memory");
    __builtin_amdgcn_s_barrier();
    __builtin_amdgcn_sched_barrier(0);   // pin: STAGE below must not cross barrier
    const int cur = jt & 1;
    if (jt + 1 < 32) STAGE(jt + 1, cur ^ 1);
    char* const Kl = smem + cur * 8192;
    char* const Vl = smem + 16384 + cur * 8192;

    // K A-frags for this jsub's 32 rows: kf[ks] = K[jsub*32+l31][ks*16+8hi ..+8]
    u32x4 kf[4];
    {
      const int row = jsub * 32 + l31;
      const int rs = (row & 7) << 4;
#pragma unroll
      for (int ks = 0; ks < 4; ks++)
        kf[ks] = *(const u32x4*)(Kl + row * 128 + (((2 * ks + hi) * 16) ^ rs));
    }

    // QK^T (swapped): st[qs] = S^T[j=jsub*32+crow(r,hi)][q=qs*32+l31]
    f32x16 st[2];
#pragma unroll
    for (int qs = 0; qs < 2; qs++)
#pragma unroll
      for (int r = 0; r < 16; r++) st[qs][r] = 0.f;
    __builtin_amdgcn_s_setprio(1);
#pragma unroll
    for (int ks = 0; ks < 4; ks++) {
      mfma32(st[0], kf[ks], qf[0][ks]);
      mfma32(st[1], kf[ks], qf[1][ks]);
    }
    __builtin_amdgcn_s_setprio(0);

    // V A-frags: vf[cb][js] = V[cb*32+l31][jsub*32+js*16+8hi ..+8]
    u32x4 vf[2][2];
#pragma unroll
    for (int cb = 0; cb < 2; cb++) {
      const int row = cb * 32 + l31;
      const int rs = (row & 7) << 4;
#pragma unroll
      for (int js = 0; js < 2; js++)
        vf[cb][js] = *(const u32x4*)(Vl + row * 128 + (((jsub * 4 + js * 2 + hi) * 16) ^ rs));
    }

    // per qs: P=exp2(S) in-register -> cvt_pk -> permlane32_swap -> PV
#pragma unroll
    for (int qs = 0; qs < 2; qs++) {
      float p[16];
#pragma unroll
      for (int r = 0; r < 16; r++) p[r] = __builtin_amdgcn_exp2f(st[qs][r]);
      lpart[qs] += (((p[0] + p[1]) + (p[2] + p[3])) + ((p[4] + p[5]) + (p[6] + p[7]))) +
                   (((p[8] + p[9]) + (p[10] + p[11])) + ((p[12] + p[13]) + (p[14] + p[15])));
      unsigned w00 = cvtpk(p[0], p[1]),   w01 = cvtpk(p[2], p[3]);
      unsigned w10 = cvtpk(p[4], p[5]),   w11 = cvtpk(p[6], p[7]);
      unsigned w20 = cvtpk(p[8], p[9]),   w21 = cvtpk(p[10], p[11]);
      unsigned w30 = cvtpk(p[12], p[13]), w31 = cvtpk(p[14], p[15]);
      asm volatile("v_permlane32_swap_b32 %0, %1" : "+v"(w00), "+v"(w10));
      asm volatile("v_permlane32_swap_b32 %0, %1" : "+v"(w01), "+v"(w11));
      asm volatile("v_permlane32_swap_b32 %0, %1" : "+v"(w20), "+v"(w30));
      asm volatile("v_permlane32_swap_b32 %0, %1" : "+v"(w21), "+v"(w31));
      u32x4 pf0, pf1;
      pf0[0] = w00; pf0[1] = w01; pf0[2] = w10; pf0[3] = w11;
      pf1[0] = w20; pf1[1] = w21; pf1[2] = w30; pf1[3] = w31;
      __builtin_amdgcn_s_setprio(1);
      mfma32(acc[0][qs], vf[0][0], pf0);
      mfma32(acc[1][qs], vf[1][0], pf0);
      mfma32(acc[0][qs], vf[0][1], pf1);
      mfma32(acc[1][qs], vf[1][1], pf1);
      __builtin_amdgcn_s_setprio(0);
    }
  }
#undef STAGE

  // full l per q over this wave's j32: add partner hi-half
#pragma unroll
  for (int qs = 0; qs < 2; qs++) lpart[qs] += __shfl_xor(lpart[qs], 32);

  // ---- jsub merge (plain sums; overlay dbuf region)
  __syncthreads();
  char* const obuf = smem + qsub * 16384;    // [64 q][64 ch] f32, XOR-swizzled
  float* const mlb = (float*)(smem + 32768); // [2 qsub][64 q] partner l
  if (jsub == 1) {
#pragma unroll
    for (int qs = 0; qs < 2; qs++) {
      const int qloc = qs * 32 + l31;
      const int qsw = (qloc & 7) << 4;
#pragma unroll
      for (int cb = 0; cb < 2; cb++)
#pragma unroll
        for (int a = 0; a < 4; a++) {
          const int ch0 = cb * 32 + 8 * a + 4 * hi;
          f32x4 v;
          v[0] = acc[cb][qs][4 * a];     v[1] = acc[cb][qs][4 * a + 1];
          v[2] = acc[cb][qs][4 * a + 2]; v[3] = acc[cb][qs][4 * a + 3];
          *(f32x4*)(obuf + qloc * 256 + ((ch0 * 4) ^ qsw)) = v;
        }
      if (hi == 0) mlb[qsub * 64 + qloc] = lpart[qs];
    }
  }
  __syncthreads();
  if (jsub == 0) {
#pragma unroll
    for (int qs = 0; qs < 2; qs++) {
      const int qloc = qs * 32 + l31;
      const int qsw = (qloc & 7) << 4;
      const int qg = qb * 128 + qsub * 64 + qloc;
      const size_t pbase = ((size_t)slice * N + qg) * 64;
#pragma unroll
      for (int cb = 0; cb < 2; cb++)
#pragma unroll
        for (int a = 0; a < 4; a++) {
          const int ch0 = cb * 32 + 8 * a + 4 * hi;
          f32x4 oo = *(const f32x4*)(obuf + qloc * 256 + ((ch0 * 4) ^ qsw));
          u32x2 pk;
          pk[0] = cvtpk(acc[cb][qs][4 * a] + oo[0], acc[cb][qs][4 * a + 1] + oo[1]);
          pk[1] = cvtpk(acc[cb][qs][4 * a + 2] + oo[2], acc[cb][qs][4 * a + 3] + oo[3]);
          *(u32x2*)(Opart + pbase + ch0) = pk;
        }
      if (hi == 0) Lsum[(size_t)slice * N + qg] = lpart[qs] + mlb[qsub * 64 + qloc];
    }
  }
}

// ---- fused merge + output projection (R14-best tail config): 32-voxel tiles, grid 256.
// Fs[dir*64+ch][q] = (sum_c Opart[slice][q][ch]) / (sum_c Lsum[slice][q]); GEMM with wo.
__global__ __launch_bounds__(256) void oproj_kernel(
    const unsigned short* __restrict__ Opart, const float* __restrict__ Lsum,
    const float* __restrict__ wo, const float* __restrict__ bo,
    float* __restrict__ out) {
  __shared__ float Fs[128][32];   // 16 KB
  __shared__ float Ws[64][128];   // 32 KB
  const int t = threadIdx.x;
  const int n0 = blockIdx.x * 32;
#pragma unroll
  for (int i = 0; i < 8; i++) {
    int s = t + i * 256;
    ((u32x4*)Ws)[s] = ((const u32x4*)wo)[s];
  }
  const int q = t & 31;     // local voxel
  const int cg = t >> 5;    // 8 groups: 2 ch4-blocks each per dir
#pragma unroll
  for (int dir = 0; dir < 2; dir++) {
    float lt = 0.f;
#pragma unroll
    for (int c = 0; c < 4; c++) lt += Lsum[(size_t)(dir * SPLIT + c) * N + n0 + q];
    const float rD = 1.0f / lt;
#pragma unroll
    for (int i = 0; i < 2; i++) {
      const int ch4 = cg * 2 + i;   // channels ch4*4 .. +4
      float s0 = 0.f, s1 = 0.f, s2 = 0.f, s3 = 0.f;
#pragma unroll
      for (int c = 0; c < 4; c++) {
        u16x4 v = *(const u16x4*)(Opart +
            ((size_t)(dir * SPLIT + c) * N + n0 + q) * 64 + ch4 * 4);
        s0 += bf2f(v[0]); s1 += bf2f(v[1]); s2 += bf2f(v[2]); s3 += bf2f(v[3]);
      }
      Fs[dir * 64 + ch4 * 4 + 0][q] = s0 * rD;
      Fs[dir * 64 + ch4 * 4 + 1][q] = s1 * rD;
      Fs[dir * 64 + ch4 * 4 + 2][q] = s2 * rD;
      Fs[dir * 64 + ch4 * 4 + 3][q] = s3 * rD;
    }
  }
  __syncthreads();
  const int n = t & 31, h = t >> 5;   // 8 outputs per thread
  float acc[8];
#pragma unroll
  for (int o = 0; o < 8; o++) acc[o] = bo[h * 8 + o];
  for (int ch = 0; ch < 128; ch++) {
    float fv = Fs[ch][n];
#pragma unroll
    for (int o = 0; o < 8; o++) acc[o] = fmaf(Ws[h * 8 + o][ch], fv, acc[o]);
  }
#pragma unroll
  for (int o = 0; o < 8; o++) out[(size_t)(h * 8 + o) * N + n0 + n] = acc[o];
}

extern "C" void kernel_launch(void* const* d_in, const int* in_sizes, int n_in,
                              void* d_out, int out_size, void* d_ws, size_t ws_size,
                              hipStream_t stream) {
  const float* ct     = (const float*)d_in[0];
  const float* mri    = (const float*)d_in[1];
  const float* wq_ct  = (const float*)d_in[2];
  const float* bq_ct  = (const float*)d_in[3];
  const float* wk_mri = (const float*)d_in[4];
  const float* bk_mri = (const float*)d_in[5];
  const float* wv_mri = (const float*)d_in[6];
  const float* bv_mri = (const float*)d_in[7];
  const float* wq_mri = (const float*)d_in[8];
  const float* bq_mri = (const float*)d_in[9];
  const float* wk_ct  = (const float*)d_in[10];
  const float* bk_ct  = (const float*)d_in[11];
  const float* wv_ct  = (const float*)d_in[12];
  const float* bv_ct  = (const float*)d_in[13];
  const float* wo     = (const float*)d_in[14];
  const float* bo     = (const float*)d_in[15];

  // ws layout: [0,6M) 6x1MB bf16 projections; [6M,14M) Opart bf16; [14M,14.5M) Lsum f32.
  char* ws = (char*)d_ws;
  const size_t MB = (size_t)1 << 20;
  unsigned short* Qt_ct  = (unsigned short*)(ws + 0 * MB);  // [n][64], pre-scaled
  unsigned short* Kt_mri = (unsigned short*)(ws + 1 * MB);  // [n][64]
  unsigned short* V_mri  = (unsigned short*)(ws + 2 * MB);  // [c][N]
  unsigned short* Qt_mri = (unsigned short*)(ws + 3 * MB);
  unsigned short* Kt_ct  = (unsigned short*)(ws + 4 * MB);
  unsigned short* V_ct   = (unsigned short*)(ws + 5 * MB);
  unsigned short* Opart  = (unsigned short*)(ws + 6 * MB);
  float* Lsum            = (float*)(ws + 14 * MB);

  ProjArgs A;
  A.x[0] = ct;  A.w[0] = wq_ct;  A.b[0] = bq_ct;  A.o[0] = Qt_ct;  A.mode[0] = 0; A.scale[0] = QSCALE;
  A.x[1] = mri; A.w[1] = wk_mri; A.b[1] = bk_mri; A.o[1] = Kt_mri; A.mode[1] = 0; A.scale[1] = 1.f;
  A.x[2] = mri; A.w[2] = wv_mri; A.b[2] = bv_mri; A.o[2] = V_mri;  A.mode[2] = 1; A.scale[2] = 1.f;
  A.x[3] = mri; A.w[3] = wq_mri; A.b[3] = bq_mri; A.o[3] = Qt_mri; A.mode[3] = 0; A.scale[3] = QSCALE;
  A.x[4] = ct;  A.w[4] = wk_ct;  A.b[4] = bk_ct;  A.o[4] = Kt_ct;  A.mode[4] = 0; A.scale[4] = 1.f;
  A.x[5] = ct;  A.w[5] = wv_ct;  A.b[5] = bv_ct;  A.o[5] = V_ct;   A.mode[5] = 1; A.scale[5] = 1.f;

  proj_kernel<<<dim3(128, 6), 256, 0, stream>>>(A);
  attn_kernel<<<dim3(512), 256, 0, stream>>>(Qt_ct, Kt_mri, V_mri,
                                             Qt_mri, Kt_ct, V_ct, Opart, Lsum);
  oproj_kernel<<<dim3(256), 256, 0, stream>>>(Opart, Lsum, wo, bo, (float*)d_out);
}